// Round 12
// baseline (560.747 us; speedup 1.0000x reference)
//
#include <hip/hip_runtime.h>
#include <hip/hip_bf16.h>

// Problem constants (match reference)
#define NB    64
#define NN    384
#define PPAIR 73536     // NN*(NN-1)/2 (reference pair count)
#define PRECT 147456    // NN*NN rectangular key space (= 144 * 1024 exactly)
#define KSEL  3677      // round(0.05 * PPAIR)

// d_out layout (FLOAT32 elements, concatenated in return order)
#define OFF_X 0
#define OFF_E 6291456
#define B2K   470656    // NB*2*KSEL
#define OFF_B 7232768
#define OFF_P 7257344
#define TOT   7492672

// ws layout (45.8 MB peak, within proven 48.1 MB bound)
#define WS_H    0ull           // h bf16: 24576*512*2        = 25165824
#define WS_SQ   25165824ull    // sq f32: 24576*4            = 98304
#define WS_W1P  25264128ull    // W1 packed: 192*512*2       = 196608
#define WS_W2P  25460736ull    // W2 packed: 512*256*2       = 262144
#define WS_WEP  25722880ull    // We packed: 256*512*2       = 262144
#define WS_T1   25985024ull    // t1 half-M bf16: 12582912 (dead after GEMM2)
#define WS_KEY  25985024ull    // keys u16 rect alias t1: 64*147456*2 = 18874368
#define WS_SEL  44859392ull    // selP u32: 64*3677*4        = 941312

typedef __attribute__((ext_vector_type(8))) short bf16x8;
typedef __attribute__((ext_vector_type(4))) float f32x4;

__device__ __forceinline__ short f2bf(float f) {
    __hip_bfloat16 h = __float2bfloat16(f);
    return *reinterpret_cast<short*>(&h);
}
__device__ __forceinline__ float bfs2f(unsigned s) {
    return __uint_as_float((s & 0xFFFFu) << 16);
}

// LDS-only barrier: waits own LDS ops, does NOT drain vmcnt — prefetched
// global loads stay in flight across the barrier.
__device__ __forceinline__ void bar_lds() {
    asm volatile("s_waitcnt lgkmcnt(0)\n\ts_barrier" ::: "memory");
}

// ---------------------------------------------------------------------------
// Fused pack: W1/W2/We f32 -> A-operand fragments of W^T (bf16), + zero sqW.
// ---------------------------------------------------------------------------
__device__ __forceinline__ void packOne(
    const float* __restrict__ W, int K, int N, short* __restrict__ dst, int idx)
{
    if (idx >= K * N) return;
    int j = idx & 7;
    int l = (idx >> 3) & 63;
    int rest = idx >> 9;
    int Kt = K >> 5;
    int kt = rest % Kt, mt = rest / Kt;
    int k = kt * 32 + (l >> 4) * 8 + j;
    int n = mt * 16 + (l & 15);
    dst[idx] = f2bf(W[(size_t)k * N + n]);
}

__global__ __launch_bounds__(256) void pack_all_kernel(
    const float* __restrict__ W1, const float* __restrict__ W2,
    const float* __restrict__ We, short* __restrict__ W1p,
    short* __restrict__ W2p, short* __restrict__ Wep, float* __restrict__ sqW)
{
    int blk = blockIdx.x, tid = threadIdx.x;
    if (blk < 384)        packOne(W1, 192, 512, W1p, blk * 256 + tid);
    else if (blk < 896)   packOne(W2, 512, 256, W2p, (blk - 384) * 256 + tid);
    else if (blk < 1408)  packOne(We, 256, 512, Wep, (blk - 896) * 256 + tid);
    else {
        int i = (blk - 1408) * 256 + tid;
        if (i < NB * NN) sqW[i] = 0.f;     // re-zeroed EVERY call (ws poisoned)
    }
}

// ---------------------------------------------------------------------------
// Templated tiled MFMA GEMM (unchanged from round 9).
// ---------------------------------------------------------------------------
template<int MODE>
__global__ __launch_bounds__(256) void gemm_t(
    const short* __restrict__ Ab, const float* __restrict__ Af,
    const int* __restrict__ cls, const float* __restrict__ et,
    const short* __restrict__ Wp, const float* __restrict__ bias,
    float* __restrict__ oF, short* __restrict__ oB, float* __restrict__ sqOut,
    int K, int N, int relu, int aBase)
{
    __shared__ short sA[128 * 72];
    const int tid = threadIdx.x;
    const int r0 = blockIdx.x * 128;
    const int f0 = blockIdx.y * 128;
    const int lane = tid & 63;
    const int l15 = lane & 15, kj = lane >> 4;
    const int aHalf = (tid >> 6) >> 1;
    const int bHalf = (tid >> 6) & 1;
    const int Kt = K >> 5;

    f32x4 acc[4][4];
#pragma unroll
    for (int t = 0; t < 4; ++t)
#pragma unroll
        for (int s = 0; s < 4; ++s) acc[t][s] = (f32x4){0.f, 0.f, 0.f, 0.f};

    int cl = (MODE == 1) ? cls[(aBase + r0) / NN] : 0;
    const int nKC = K >> 6;

    int4  rI[4];
    float4 rA[4], rB[4];

    auto issueLoads = [&](int kc) {
#pragma unroll
        for (int q = 0; q < 4; ++q) {
            int e = tid + (q << 8);
            int row = e >> 3, c8 = e & 7;
            int col = (kc << 6) + (c8 << 3);
            if (MODE == 0) {
                rI[q] = *(const int4*)(Ab + (size_t)(r0 + row) * K + col);
            } else if (MODE == 1) {
                if (col < 128) {
                    const float* src = Af + (size_t)(aBase + r0 + row) * 128 + col;
                    rA[q] = *(const float4*)src; rB[q] = *(const float4*)(src + 4);
                } else {
                    const float* src = et + cl * 64 + (col - 128);
                    rA[q] = *(const float4*)src; rB[q] = *(const float4*)(src + 4);
                }
            } else {
                const float* src = Af + (size_t)(r0 + row) * 256 + col;
                rA[q] = *(const float4*)src; rB[q] = *(const float4*)(src + 4);
            }
        }
    };
    auto storeStage = [&]() {
#pragma unroll
        for (int q = 0; q < 4; ++q) {
            int e = tid + (q << 8);
            int row = e >> 3, c8 = e & 7;
            int4 v;
            if (MODE == 0) {
                v = rI[q];
            } else {
                v.x = (unsigned short)f2bf(rA[q].x) | ((unsigned)(unsigned short)f2bf(rA[q].y) << 16);
                v.y = (unsigned short)f2bf(rA[q].z) | ((unsigned)(unsigned short)f2bf(rA[q].w) << 16);
                v.z = (unsigned short)f2bf(rB[q].x) | ((unsigned)(unsigned short)f2bf(rB[q].y) << 16);
                v.w = (unsigned short)f2bf(rB[q].z) | ((unsigned)(unsigned short)f2bf(rB[q].w) << 16);
            }
            *(int4*)(sA + row * 72 + (c8 << 3)) = v;
        }
    };

    issueLoads(0);
    for (int kc = 0; kc < nKC; ++kc) {
        storeStage();
        if (kc + 1 < nKC) issueLoads(kc + 1);
        bar_lds();
#pragma unroll
        for (int kt2 = 0; kt2 < 2; ++kt2) {
            int kt = (kc << 1) + kt2;
            bf16x8 aF[4], bF[4];
#pragma unroll
            for (int t = 0; t < 4; ++t) {
                int mt = (f0 >> 4) + aHalf * 4 + t;
                aF[t] = *(const bf16x8*)(Wp + ((size_t)(mt * Kt + kt) << 9) + (lane << 3));
            }
#pragma unroll
            for (int s = 0; s < 4; ++s)
                bF[s] = *(const bf16x8*)(sA + (bHalf * 64 + s * 16 + l15) * 72 + kt2 * 32 + (kj << 3));
#pragma unroll
            for (int t = 0; t < 4; ++t)
#pragma unroll
                for (int s = 0; s < 4; ++s)
                    acc[t][s] = __builtin_amdgcn_mfma_f32_16x16x32_bf16(aF[t], bF[s], acc[t][s], 0, 0, 0);
        }
        bar_lds();
    }

    float sqp[4] = {0.f, 0.f, 0.f, 0.f};
#pragma unroll
    for (int t = 0; t < 4; ++t) {
        int featBase = f0 + (aHalf * 4 + t) * 16 + (kj << 2);
        float4 bv = *(const float4*)(bias + featBase);
#pragma unroll
        for (int s = 0; s < 4; ++s) {
            int node = r0 + bHalf * 64 + s * 16 + l15;
            f32x4 a = acc[t][s];
            float v0 = a.x + bv.x, v1 = a.y + bv.y, v2 = a.z + bv.z, v3 = a.w + bv.w;
            if (relu) {
                v0 = fmaxf(v0, 0.f); v1 = fmaxf(v1, 0.f);
                v2 = fmaxf(v2, 0.f); v3 = fmaxf(v3, 0.f);
            }
            if (oF) {
                float4 o; o.x = v0; o.y = v1; o.z = v2; o.w = v3;
                *(float4*)(oF + (size_t)(aBase + node) * N + featBase) = o;
            }
            if (oB) {
                short s0 = f2bf(v0), s1 = f2bf(v1), s2 = f2bf(v2), s3 = f2bf(v3);
                int2 pk;
                pk.x = (unsigned short)s0 | ((unsigned)(unsigned short)s1 << 16);
                pk.y = (unsigned short)s2 | ((unsigned)(unsigned short)s3 << 16);
                *(int2*)(oB + (size_t)node * N + featBase) = pk;
                if (sqOut) {
                    float h0 = bfs2f((unsigned short)s0), h1 = bfs2f((unsigned short)s1);
                    float h2 = bfs2f((unsigned short)s2), h3 = bfs2f((unsigned short)s3);
                    sqp[s] += h0 * h0 + h1 * h1 + h2 * h2 + h3 * h3;
                }
            }
        }
    }
    if (oB && sqOut) {
#pragma unroll
        for (int s = 0; s < 4; ++s) {
            float v = sqp[s];
            v += __shfl_xor(v, 16);
            v += __shfl_xor(v, 32);
            if (kj == 0)
                atomicAdd(sqOut + aBase + r0 + bHalf * 64 + s * 16 + l15, v);
        }
    }
}

// ---------------------------------------------------------------------------
// MFMA gram -> d2 -> u16 keys into RECTANGULAR layout key[b][gi][384].
// Grid dim3(64 graphs, 21 tile-pairs) -> graph b's blocks share XCD b%8.
// Lower-half rect cells stay poison (key>=0x8000 -> skipped by select).
// ---------------------------------------------------------------------------
__global__ __launch_bounds__(256) void gram_mfma_kernel(
    const short* __restrict__ hW, const float* __restrict__ sqW,
    unsigned short* __restrict__ keyW)
{
    extern __shared__ short smem[];
    short* As = smem;            // [64][136]
    short* Bs = smem + 8704;     // [64][136]

    const int tid = threadIdx.x;
    const int b  = blockIdx.x;
    int tp = blockIdx.y;
    int ti = 0; { int rem = tp; while (rem >= 6 - ti) { rem -= 6 - ti; ++ti; } tp = rem; }
    const int tj = ti + tp;
    const bool diag = (ti == tj);
    const short* Bp = diag ? As : Bs;

    const int w = tid >> 6;
    const int lane = tid & 63;
    const int l15 = lane & 15, kj = lane >> 4;
    const int mb = w * 16;

    f32x4 acc[4];
#pragma unroll
    for (int t = 0; t < 4; ++t) acc[t] = (f32x4){0.f, 0.f, 0.f, 0.f};

    const size_t baseA = ((size_t)b * NN + ti * 64) * 512;
    const size_t baseB = ((size_t)b * NN + tj * 64) * 512;

    int4 pa[4], pb[4];
    auto issue = [&](int kc) {
#pragma unroll
        for (int q = 0; q < 4; ++q) {
            int i = tid + (q << 8);
            int row = i >> 4, g = i & 15;
            pa[q] = *(const int4*)(hW + baseA + row * 512 + kc * 128 + g * 8);
            if (!diag)
                pb[q] = *(const int4*)(hW + baseB + row * 512 + kc * 128 + g * 8);
        }
    };
    auto store = [&]() {
#pragma unroll
        for (int q = 0; q < 4; ++q) {
            int i = tid + (q << 8);
            int row = i >> 4, g = i & 15;
            *(int4*)(As + row * 136 + g * 8) = pa[q];
            if (!diag) *(int4*)(Bs + row * 136 + g * 8) = pb[q];
        }
    };

    issue(0);
    for (int kc = 0; kc < 4; ++kc) {
        store();
        if (kc < 3) issue(kc + 1);
        bar_lds();
#pragma unroll
        for (int kt = 0; kt < 4; ++kt) {
            bf16x8 aF = *(const bf16x8*)(As + (mb + l15) * 136 + kt * 32 + kj * 8);
#pragma unroll
            for (int nt = 0; nt < 4; ++nt) {
                bf16x8 bF = *(const bf16x8*)(Bp + (nt * 16 + l15) * 136 + kt * 32 + kj * 8);
                acc[nt] = __builtin_amdgcn_mfma_f32_16x16x32_bf16(aF, bF, acc[nt], 0, 0, 0);
            }
        }
        bar_lds();
    }

    // ---- epilogue: keys -> LDS u16 tile [64][72] -> coalesced row writes ----
    unsigned short* tile = (unsigned short*)smem;   // reuse As region
    float4 sqi = *(const float4*)(sqW + b * NN + ti * 64 + mb + kj * 4);
    float si[4] = { sqi.x, sqi.y, sqi.z, sqi.w };
#pragma unroll
    for (int nt = 0; nt < 4; ++nt) {
        int colL = nt * 16 + l15;
        float sj = sqW[b * NN + tj * 64 + colL];
        float av[4] = { acc[nt].x, acc[nt].y, acc[nt].z, acc[nt].w };
#pragma unroll
        for (int r = 0; r < 4; ++r) {
            int rowL = mb + kj * 4 + r;
            float d2 = fmaxf(si[r] + sj - 2.f * av[r], 0.f);
            unsigned short key = (unsigned short)(__float_as_uint(d2) >> 16);
            bool valid = !diag || (rowL < colL);
            tile[rowL * 72 + colL] = valid ? key : (unsigned short)0xFFFF;
        }
    }
    bar_lds();
#pragma unroll
    for (int it = 0; it < 2; ++it) {
        int idx = tid + (it << 8);          // 0..511
        int row = idx >> 3, c8 = idx & 7;
        int4 v = *(const int4*)(tile + row * 72 + c8 * 8);
        *(int4*)(keyW + (size_t)b * PRECT + (size_t)(ti * 64 + row) * NN
                 + tj * 64 + c8 * 8) = v;
    }
}

// ---------------------------------------------------------------------------
// Counting-scatter top-K with WAVE-AGGREGATED LDS atomics.
// d2 keys are concentrated in few bins (measured: 3.7M DS conflicts in r11's
// per-lane atomics). Emulated match-any: per distinct bin in the wave, one
// leader lane does ONE atomicAdd of the group's popcount; scatter pass gives
// each lane base+rank. Keys >= 0x8000 (poison/diag) are excluded.
// ---------------------------------------------------------------------------
__global__ __launch_bounds__(1024) void select_kernel(
    const unsigned short* __restrict__ keyW, unsigned* __restrict__ selP)
{
    const int b = blockIdx.x, tid = threadIdx.x;
    const int lane = tid & 63;
    const unsigned short* keys = keyW + (size_t)b * PRECT;
    __shared__ unsigned hist[4096];
    __shared__ unsigned base[4096];
    __shared__ unsigned scanBuf[1024];
    __shared__ int sTc;

    for (int i = tid; i < 4096; i += 1024) hist[i] = 0;
    if (tid == 0) sTc = 4095;
    __syncthreads();

    // ---- pass 1: histogram, wave-aggregated ----
    for (int p = tid; p < PRECT; p += 1024) {       // PRECT = 144*1024 exact
        unsigned k = keys[p];
        int bin = (k < 0x8000u) ? (int)(k >> 4) : -1;
        unsigned long long todo = ~0ull;
        while (todo) {
            int leader = (int)__builtin_ctzll(todo);
            int lbin = __shfl(bin, leader);
            unsigned long long mask = __ballot(bin == lbin);
            if (lane == leader && lbin >= 0)
                atomicAdd(&hist[lbin], (unsigned)__popcll(mask));
            todo &= ~mask;
        }
    }
    __syncthreads();

    // ---- scan 4096 bins ----
    unsigned c0 = hist[tid * 4], c1 = hist[tid * 4 + 1];
    unsigned c2 = hist[tid * 4 + 2], c3 = hist[tid * 4 + 3];
    unsigned tsum = c0 + c1 + c2 + c3;
    scanBuf[tid] = tsum;
    __syncthreads();
    for (int o = 1; o < 1024; o <<= 1) {
        unsigned v = (tid >= o) ? scanBuf[tid - o] : 0u;
        __syncthreads();
        scanBuf[tid] += v;
        __syncthreads();
    }
    unsigned exc = scanBuf[tid] - tsum;
    base[tid * 4]     = exc;
    base[tid * 4 + 1] = exc + c0;
    base[tid * 4 + 2] = exc + c0 + c1;
    base[tid * 4 + 3] = exc + c0 + c1 + c2;
    __syncthreads();

#pragma unroll
    for (int q = 0; q < 4; ++q) {
        int i = tid * 4 + q;
        if (base[i] < KSEL && base[i] + hist[i] >= KSEL) atomicMin(&sTc, i);
    }
    __syncthreads();
    int T = sTc;

    for (int i = tid; i < 4096; i += 1024) hist[i] = 0;
    __syncthreads();

    // ---- pass 2: scatter, wave-aggregated base + per-lane rank ----
    for (int p = tid; p < PRECT; p += 1024) {
        unsigned k = keys[p];
        int bin = (k < 0x8000u && (int)(k >> 4) <= T) ? (int)(k >> 4) : -1;
        unsigned long long todo = ~0ull;
        while (todo) {
            int leader = (int)__builtin_ctzll(todo);
            int lbin = __shfl(bin, leader);
            unsigned long long mask = __ballot(bin == lbin);
            unsigned wbase = 0;
            if (lane == leader && lbin >= 0)
                wbase = atomicAdd(&hist[lbin], (unsigned)__popcll(mask));
            wbase = __shfl(wbase, leader);
            if (lbin >= 0 && bin == lbin) {
                unsigned rank = (unsigned)__popcll(mask & ((1ull << lane) - 1ull));
                unsigned pos = base[lbin] + wbase + rank;
                if (pos < KSEL) selP[(size_t)b * KSEL + pos] = (unsigned)p;
            }
            todo &= ~mask;
        }
    }
}

// ---------------------------------------------------------------------------
// emit edge_index, batch, top_probs as FLOAT32 ([OFF_E, TOT)).
// Rect pair decode: i = p/384, j = p%384.
// ---------------------------------------------------------------------------
__global__ __launch_bounds__(256) void emit_kernel(
    const unsigned short* __restrict__ keyW, const unsigned* __restrict__ selP,
    const float* __restrict__ thrp, float* __restrict__ outF)
{
    long long idx = OFF_E + (long long)blockIdx.x * 256 + threadIdx.x;
    if (idx >= TOT) return;

    if (idx < OFF_B) {                       // edge_index
        long long q = idx - OFF_E;
        int row = (int)(q / B2K);
        int rem = (int)(q - (long long)row * B2K);
        int b = rem / (2 * KSEL);
        int t = rem - b * (2 * KSEL);
        int slot = (t < KSEL) ? t : (t - KSEL);
        unsigned p = selP[(size_t)b * KSEL + slot];
        if (p >= PRECT) p = 1;
        int i = p / NN;
        int j = p - i * NN;
        bool first = (t < KSEL);
        int node = (row == 0) ? (first ? i : j) : (first ? j : i);
        outF[idx] = (float)(b * NN + node);
        return;
    }
    if (idx < OFF_P) {                       // batch
        int m = (int)(idx - OFF_B);
        outF[idx] = (float)(m / NN);
        return;
    }
    {                                        // top_probs
        int m = (int)(idx - OFF_P);
        int b = m / KSEL;
        int k = m - b * KSEL;
        unsigned p = selP[(size_t)b * KSEL + k];
        if (p >= PRECT) p = 1;
        unsigned short key = keyW[(size_t)b * PRECT + p];
        float d2 = __uint_as_float(((unsigned)key) << 16);
        float dist = sqrtf(fmaxf(d2, 1e-12f));
        outF[idx] = 1.0f / (1.0f + expf(dist - thrp[0]));
    }
}

// ---------------------------------------------------------------------------
extern "C" void kernel_launch(void* const* d_in, const int* in_sizes, int n_in,
                              void* d_out, int out_size, void* d_ws, size_t ws_size,
                              hipStream_t stream) {
    (void)in_sizes; (void)n_in; (void)out_size; (void)ws_size;
    const float* z   = (const float*)d_in[0];
    const int*   cls = (const int*)d_in[1];
    const float* et  = (const float*)d_in[2];
    const float* W1  = (const float*)d_in[3];
    const float* b1  = (const float*)d_in[4];
    const float* W2  = (const float*)d_in[5];
    const float* b2  = (const float*)d_in[6];
    const float* We  = (const float*)d_in[7];
    const float* be  = (const float*)d_in[8];
    const float* thr = (const float*)d_in[9];
    float* outF = (float*)d_out;

    char* w = (char*)d_ws;
    short*          hW   = (short*)(w + WS_H);
    float*          sqW  = (float*)(w + WS_SQ);
    short*          W1p  = (short*)(w + WS_W1P);
    short*          W2p  = (short*)(w + WS_W2P);
    short*          Wep  = (short*)(w + WS_WEP);
    short*          t1   = (short*)(w + WS_T1);
    unsigned short* keyW = (unsigned short*)(w + WS_KEY);
    unsigned*       selP = (unsigned*)(w + WS_SEL);

    pack_all_kernel<<<1504, 256, 0, stream>>>(W1, W2, We, W1p, W2p, Wep, sqW);

    for (int h = 0; h < 2; ++h) {
        int aBase = h * 12288;
        gemm_t<1><<<dim3(96, 4), 256, 0, stream>>>(
            nullptr, z, cls, et, W1p, b1, nullptr, t1, nullptr, 192, 512, 1, aBase);
        gemm_t<0><<<dim3(96, 2), 256, 0, stream>>>(
            t1, nullptr, nullptr, nullptr, W2p, b2, outF + OFF_X, nullptr, nullptr,
            512, 256, 0, aBase);
    }
    gemm_t<2><<<dim3(192, 4), 256, 0, stream>>>(
        nullptr, outF + OFF_X, nullptr, nullptr, Wep, be, nullptr, hW, sqW,
        256, 512, 1, 0);

    gram_mfma_kernel<<<dim3(64, 21), 256, 34816, stream>>>(hW, sqW, keyW);
    select_kernel<<<64, 1024, 0, stream>>>(keyW, selP);
    int emitN = TOT - OFF_E;
    emit_kernel<<<(emitN + 255) / 256, 256, 0, stream>>>(keyW, selP, thr, outF);
}

// Round 13
// 368.673 us; speedup vs baseline: 1.5210x; 1.5210x over previous
//
#include <hip/hip_runtime.h>
#include <hip/hip_bf16.h>

// Problem constants (match reference)
#define NB    64
#define NN    384
#define PPAIR 73536     // NN*(NN-1)/2 (reference pair count)
#define PRECT 147456    // NN*NN rectangular key space (= 144 * 1024 exactly)
#define KSEL  3677      // round(0.05 * PPAIR)

// d_out layout (FLOAT32 elements, concatenated in return order)
#define OFF_X 0
#define OFF_E 6291456
#define B2K   470656    // NB*2*KSEL
#define OFF_B 7232768
#define OFF_P 7257344
#define TOT   7492672

// ws layout (45.8 MB peak, within proven 48.1 MB bound)
#define WS_H    0ull           // h bf16: 24576*512*2        = 25165824
#define WS_SQ   25165824ull    // sq f32: 24576*4            = 98304
#define WS_W1P  25264128ull    // W1 packed: 192*512*2       = 196608
#define WS_W2P  25460736ull    // W2 packed: 512*256*2       = 262144
#define WS_WEP  25722880ull    // We packed: 256*512*2       = 262144
#define WS_T1   25985024ull    // t1 half-M bf16: 12582912 (dead after GEMM2)
#define WS_KEY  25985024ull    // keys u16 rect alias t1: 64*147456*2 = 18874368
#define WS_SEL  44859392ull    // selP u32: 64*3677*4        = 941312

typedef __attribute__((ext_vector_type(8))) short bf16x8;
typedef __attribute__((ext_vector_type(4))) float f32x4;

__device__ __forceinline__ short f2bf(float f) {
    __hip_bfloat16 h = __float2bfloat16(f);
    return *reinterpret_cast<short*>(&h);
}
__device__ __forceinline__ float bfs2f(unsigned s) {
    return __uint_as_float((s & 0xFFFFu) << 16);
}

// LDS-only barrier: waits own LDS ops, does NOT drain vmcnt — prefetched
// global loads stay in flight across the barrier.
__device__ __forceinline__ void bar_lds() {
    asm volatile("s_waitcnt lgkmcnt(0)\n\ts_barrier" ::: "memory");
}

// ---------------------------------------------------------------------------
// Fused pack: W1/W2/We f32 -> A-operand fragments of W^T (bf16), + zero sqW.
// ---------------------------------------------------------------------------
__device__ __forceinline__ void packOne(
    const float* __restrict__ W, int K, int N, short* __restrict__ dst, int idx)
{
    if (idx >= K * N) return;
    int j = idx & 7;
    int l = (idx >> 3) & 63;
    int rest = idx >> 9;
    int Kt = K >> 5;
    int kt = rest % Kt, mt = rest / Kt;
    int k = kt * 32 + (l >> 4) * 8 + j;
    int n = mt * 16 + (l & 15);
    dst[idx] = f2bf(W[(size_t)k * N + n]);
}

__global__ __launch_bounds__(256) void pack_all_kernel(
    const float* __restrict__ W1, const float* __restrict__ W2,
    const float* __restrict__ We, short* __restrict__ W1p,
    short* __restrict__ W2p, short* __restrict__ Wep, float* __restrict__ sqW)
{
    int blk = blockIdx.x, tid = threadIdx.x;
    if (blk < 384)        packOne(W1, 192, 512, W1p, blk * 256 + tid);
    else if (blk < 896)   packOne(W2, 512, 256, W2p, (blk - 384) * 256 + tid);
    else if (blk < 1408)  packOne(We, 256, 512, Wep, (blk - 896) * 256 + tid);
    else {
        int i = (blk - 1408) * 256 + tid;
        if (i < NB * NN) sqW[i] = 0.f;     // re-zeroed EVERY call (ws poisoned)
    }
}

// ---------------------------------------------------------------------------
// Templated tiled MFMA GEMM (unchanged from round 9).
// ---------------------------------------------------------------------------
template<int MODE>
__global__ __launch_bounds__(256) void gemm_t(
    const short* __restrict__ Ab, const float* __restrict__ Af,
    const int* __restrict__ cls, const float* __restrict__ et,
    const short* __restrict__ Wp, const float* __restrict__ bias,
    float* __restrict__ oF, short* __restrict__ oB, float* __restrict__ sqOut,
    int K, int N, int relu, int aBase)
{
    __shared__ short sA[128 * 72];
    const int tid = threadIdx.x;
    const int r0 = blockIdx.x * 128;
    const int f0 = blockIdx.y * 128;
    const int lane = tid & 63;
    const int l15 = lane & 15, kj = lane >> 4;
    const int aHalf = (tid >> 6) >> 1;
    const int bHalf = (tid >> 6) & 1;
    const int Kt = K >> 5;

    f32x4 acc[4][4];
#pragma unroll
    for (int t = 0; t < 4; ++t)
#pragma unroll
        for (int s = 0; s < 4; ++s) acc[t][s] = (f32x4){0.f, 0.f, 0.f, 0.f};

    int cl = (MODE == 1) ? cls[(aBase + r0) / NN] : 0;
    const int nKC = K >> 6;

    int4  rI[4];
    float4 rA[4], rB[4];

    auto issueLoads = [&](int kc) {
#pragma unroll
        for (int q = 0; q < 4; ++q) {
            int e = tid + (q << 8);
            int row = e >> 3, c8 = e & 7;
            int col = (kc << 6) + (c8 << 3);
            if (MODE == 0) {
                rI[q] = *(const int4*)(Ab + (size_t)(r0 + row) * K + col);
            } else if (MODE == 1) {
                if (col < 128) {
                    const float* src = Af + (size_t)(aBase + r0 + row) * 128 + col;
                    rA[q] = *(const float4*)src; rB[q] = *(const float4*)(src + 4);
                } else {
                    const float* src = et + cl * 64 + (col - 128);
                    rA[q] = *(const float4*)src; rB[q] = *(const float4*)(src + 4);
                }
            } else {
                const float* src = Af + (size_t)(r0 + row) * 256 + col;
                rA[q] = *(const float4*)src; rB[q] = *(const float4*)(src + 4);
            }
        }
    };
    auto storeStage = [&]() {
#pragma unroll
        for (int q = 0; q < 4; ++q) {
            int e = tid + (q << 8);
            int row = e >> 3, c8 = e & 7;
            int4 v;
            if (MODE == 0) {
                v = rI[q];
            } else {
                v.x = (unsigned short)f2bf(rA[q].x) | ((unsigned)(unsigned short)f2bf(rA[q].y) << 16);
                v.y = (unsigned short)f2bf(rA[q].z) | ((unsigned)(unsigned short)f2bf(rA[q].w) << 16);
                v.z = (unsigned short)f2bf(rB[q].x) | ((unsigned)(unsigned short)f2bf(rB[q].y) << 16);
                v.w = (unsigned short)f2bf(rB[q].z) | ((unsigned)(unsigned short)f2bf(rB[q].w) << 16);
            }
            *(int4*)(sA + row * 72 + (c8 << 3)) = v;
        }
    };

    issueLoads(0);
    for (int kc = 0; kc < nKC; ++kc) {
        storeStage();
        if (kc + 1 < nKC) issueLoads(kc + 1);
        bar_lds();
#pragma unroll
        for (int kt2 = 0; kt2 < 2; ++kt2) {
            int kt = (kc << 1) + kt2;
            bf16x8 aF[4], bF[4];
#pragma unroll
            for (int t = 0; t < 4; ++t) {
                int mt = (f0 >> 4) + aHalf * 4 + t;
                aF[t] = *(const bf16x8*)(Wp + ((size_t)(mt * Kt + kt) << 9) + (lane << 3));
            }
#pragma unroll
            for (int s = 0; s < 4; ++s)
                bF[s] = *(const bf16x8*)(sA + (bHalf * 64 + s * 16 + l15) * 72 + kt2 * 32 + (kj << 3));
#pragma unroll
            for (int t = 0; t < 4; ++t)
#pragma unroll
                for (int s = 0; s < 4; ++s)
                    acc[t][s] = __builtin_amdgcn_mfma_f32_16x16x32_bf16(aF[t], bF[s], acc[t][s], 0, 0, 0);
        }
        bar_lds();
    }

    float sqp[4] = {0.f, 0.f, 0.f, 0.f};
#pragma unroll
    for (int t = 0; t < 4; ++t) {
        int featBase = f0 + (aHalf * 4 + t) * 16 + (kj << 2);
        float4 bv = *(const float4*)(bias + featBase);
#pragma unroll
        for (int s = 0; s < 4; ++s) {
            int node = r0 + bHalf * 64 + s * 16 + l15;
            f32x4 a = acc[t][s];
            float v0 = a.x + bv.x, v1 = a.y + bv.y, v2 = a.z + bv.z, v3 = a.w + bv.w;
            if (relu) {
                v0 = fmaxf(v0, 0.f); v1 = fmaxf(v1, 0.f);
                v2 = fmaxf(v2, 0.f); v3 = fmaxf(v3, 0.f);
            }
            if (oF) {
                float4 o; o.x = v0; o.y = v1; o.z = v2; o.w = v3;
                *(float4*)(oF + (size_t)(aBase + node) * N + featBase) = o;
            }
            if (oB) {
                short s0 = f2bf(v0), s1 = f2bf(v1), s2 = f2bf(v2), s3 = f2bf(v3);
                int2 pk;
                pk.x = (unsigned short)s0 | ((unsigned)(unsigned short)s1 << 16);
                pk.y = (unsigned short)s2 | ((unsigned)(unsigned short)s3 << 16);
                *(int2*)(oB + (size_t)node * N + featBase) = pk;
                if (sqOut) {
                    float h0 = bfs2f((unsigned short)s0), h1 = bfs2f((unsigned short)s1);
                    float h2 = bfs2f((unsigned short)s2), h3 = bfs2f((unsigned short)s3);
                    sqp[s] += h0 * h0 + h1 * h1 + h2 * h2 + h3 * h3;
                }
            }
        }
    }
    if (oB && sqOut) {
#pragma unroll
        for (int s = 0; s < 4; ++s) {
            float v = sqp[s];
            v += __shfl_xor(v, 16);
            v += __shfl_xor(v, 32);
            if (kj == 0)
                atomicAdd(sqOut + aBase + r0 + bHalf * 64 + s * 16 + l15, v);
        }
    }
}

// ---------------------------------------------------------------------------
// MFMA gram -> d2 -> u16 keys into RECTANGULAR layout key[b][gi][384].
// Grid dim3(64 graphs, 21 tile-pairs) -> graph b's blocks share XCD b%8.
// Lower-half rect cells stay poison (key>=0x8000 -> never selected).
// ---------------------------------------------------------------------------
__global__ __launch_bounds__(256) void gram_mfma_kernel(
    const short* __restrict__ hW, const float* __restrict__ sqW,
    unsigned short* __restrict__ keyW)
{
    extern __shared__ short smem[];
    short* As = smem;            // [64][136]
    short* Bs = smem + 8704;     // [64][136]

    const int tid = threadIdx.x;
    const int b  = blockIdx.x;
    int tp = blockIdx.y;
    int ti = 0; { int rem = tp; while (rem >= 6 - ti) { rem -= 6 - ti; ++ti; } tp = rem; }
    const int tj = ti + tp;
    const bool diag = (ti == tj);
    const short* Bp = diag ? As : Bs;

    const int w = tid >> 6;
    const int lane = tid & 63;
    const int l15 = lane & 15, kj = lane >> 4;
    const int mb = w * 16;

    f32x4 acc[4];
#pragma unroll
    for (int t = 0; t < 4; ++t) acc[t] = (f32x4){0.f, 0.f, 0.f, 0.f};

    const size_t baseA = ((size_t)b * NN + ti * 64) * 512;
    const size_t baseB = ((size_t)b * NN + tj * 64) * 512;

    int4 pa[4], pb[4];
    auto issue = [&](int kc) {
#pragma unroll
        for (int q = 0; q < 4; ++q) {
            int i = tid + (q << 8);
            int row = i >> 4, g = i & 15;
            pa[q] = *(const int4*)(hW + baseA + row * 512 + kc * 128 + g * 8);
            if (!diag)
                pb[q] = *(const int4*)(hW + baseB + row * 512 + kc * 128 + g * 8);
        }
    };
    auto store = [&]() {
#pragma unroll
        for (int q = 0; q < 4; ++q) {
            int i = tid + (q << 8);
            int row = i >> 4, g = i & 15;
            *(int4*)(As + row * 136 + g * 8) = pa[q];
            if (!diag) *(int4*)(Bs + row * 136 + g * 8) = pb[q];
        }
    };

    issue(0);
    for (int kc = 0; kc < 4; ++kc) {
        store();
        if (kc < 3) issue(kc + 1);
        bar_lds();
#pragma unroll
        for (int kt = 0; kt < 4; ++kt) {
            bf16x8 aF = *(const bf16x8*)(As + (mb + l15) * 136 + kt * 32 + kj * 8);
#pragma unroll
            for (int nt = 0; nt < 4; ++nt) {
                bf16x8 bF = *(const bf16x8*)(Bp + (nt * 16 + l15) * 136 + kt * 32 + kj * 8);
                acc[nt] = __builtin_amdgcn_mfma_f32_16x16x32_bf16(aF, bF, acc[nt], 0, 0, 0);
            }
        }
        bar_lds();
    }

    // ---- epilogue: keys -> LDS u16 tile [64][72] -> coalesced row writes ----
    unsigned short* tile = (unsigned short*)smem;   // reuse As region
    float4 sqi = *(const float4*)(sqW + b * NN + ti * 64 + mb + kj * 4);
    float si[4] = { sqi.x, sqi.y, sqi.z, sqi.w };
#pragma unroll
    for (int nt = 0; nt < 4; ++nt) {
        int colL = nt * 16 + l15;
        float sj = sqW[b * NN + tj * 64 + colL];
        float av[4] = { acc[nt].x, acc[nt].y, acc[nt].z, acc[nt].w };
#pragma unroll
        for (int r = 0; r < 4; ++r) {
            int rowL = mb + kj * 4 + r;
            float d2 = fmaxf(si[r] + sj - 2.f * av[r], 0.f);
            unsigned short key = (unsigned short)(__float_as_uint(d2) >> 16);
            bool valid = !diag || (rowL < colL);
            tile[rowL * 72 + colL] = valid ? key : (unsigned short)0xFFFF;
        }
    }
    bar_lds();
#pragma unroll
    for (int it = 0; it < 2; ++it) {
        int idx = tid + (it << 8);          // 0..511
        int row = idx >> 3, c8 = idx & 7;
        int4 v = *(const int4*)(tile + row * 72 + c8 * 8);
        *(int4*)(keyW + (size_t)b * PRECT + (size_t)(ti * 64 + row) * NN
                 + tj * 64 + c8 * 8) = v;
    }
}

// ---------------------------------------------------------------------------
// Select v4: exact-key two-round radix histogram with LANE-REPLICATED counts
// (hist[bin][lane]: every lane hits a distinct LDS address -> zero intra-wave
// same-address serialization; cross-wave overlap = separate wave-ops, free).
// 15-bit valid keys => round 1 on key>>7 (256 bins), round 2 on key&127
// inside the boundary bin => EXACT threshold key T. Scatter uses binary
// predicates (key<T, key==T) with one ballot + one atomic per wave — the
// aggregation trick where distinct==1 actually holds (r12 lesson).
// ---------------------------------------------------------------------------
__global__ __launch_bounds__(1024) void select_kernel(
    const unsigned short* __restrict__ keyW, unsigned* __restrict__ selP)
{
    const int b = blockIdx.x, tid = threadIdx.x;
    const int lane = tid & 63;
    const unsigned short* keys = keyW + (size_t)b * PRECT;

    __shared__ unsigned histR[256 * 64];   // 64 KB, lane-replicated
    __shared__ unsigned binTot[256];
    __shared__ unsigned sC, sBelowC, sTkey, sBelowStrict;
    __shared__ unsigned cntA, cntB;

    // ---- round 1: coarse histogram of key>>7 ----
    for (int i = tid; i < 256 * 64; i += 1024) histR[i] = 0;
    __syncthreads();
    for (int p = tid; p < PRECT; p += 1024) {
        unsigned k = keys[p];
        if (k < 0x8000u)
            atomicAdd(&histR[((k >> 7) << 6) + lane], 1u);
    }
    __syncthreads();
    if (tid < 256) {
        unsigned s = 0;
        for (int l = 0; l < 64; ++l) s += histR[(tid << 6) + l];
        binTot[tid] = s;
    }
    __syncthreads();
    if (tid == 0) {
        unsigned cum = 0; unsigned C = 255, below = 0;
        for (int i = 0; i < 256; ++i) {
            if (cum + binTot[i] >= KSEL) { C = i; below = cum; break; }
            cum += binTot[i];
        }
        sC = C; sBelowC = below;
    }
    __syncthreads();
    unsigned C = sC, belowC = sBelowC;

    // ---- round 2: fine histogram of key&127 within coarse bin C ----
    for (int i = tid; i < 128 * 64; i += 1024) histR[i] = 0;
    __syncthreads();
    for (int p = tid; p < PRECT; p += 1024) {
        unsigned k = keys[p];
        if (k < 0x8000u && (k >> 7) == C)
            atomicAdd(&histR[((k & 127u) << 6) + lane], 1u);
    }
    __syncthreads();
    if (tid < 128) {
        unsigned s = 0;
        for (int l = 0; l < 64; ++l) s += histR[(tid << 6) + l];
        binTot[tid] = s;
    }
    __syncthreads();
    if (tid == 0) {
        unsigned cum = belowC; unsigned tl = 127;
        for (int i = 0; i < 128; ++i) {
            if (cum + binTot[i] >= KSEL) { tl = i; break; }
            cum += binTot[i];
        }
        sTkey = (C << 7) | tl;
        sBelowStrict = cum;               // #(key < Tkey)
        cntA = 0; cntB = cum;             // tie positions start after stricts
    }
    __syncthreads();
    unsigned Tkey = sTkey;

    // ---- scatter: strict-below (all kept) + ties (capped at KSEL) ----
    for (int p = tid; p < PRECT; p += 1024) {
        unsigned k = keys[p];
        bool pa = (k < Tkey);             // poison >= 0x8000 > Tkey: excluded
        bool pb = (k == Tkey);
        unsigned long long mA = __ballot(pa);
        unsigned long long mB = __ballot(pb);
        if (!(mA | mB)) continue;
        unsigned bA = 0, bB = 0;
        if (lane == 0) {
            if (mA) bA = atomicAdd(&cntA, (unsigned)__popcll(mA));
            if (mB) bB = atomicAdd(&cntB, (unsigned)__popcll(mB));
        }
        bA = __shfl(bA, 0); bB = __shfl(bB, 0);
        unsigned long long lt = (lane == 63) ? 0x7FFFFFFFFFFFFFFFull
                                             : ((1ull << lane) - 1ull);
        if (pa) {
            unsigned pos = bA + (unsigned)__popcll(mA & lt);
            selP[(size_t)b * KSEL + pos] = (unsigned)p;
        } else if (pb) {
            unsigned pos = bB + (unsigned)__popcll(mB & lt);
            if (pos < KSEL) selP[(size_t)b * KSEL + pos] = (unsigned)p;
        }
    }
}

// ---------------------------------------------------------------------------
// emit edge_index, batch, top_probs as FLOAT32 ([OFF_E, TOT)).
// Rect pair decode: i = p/384, j = p%384.
// ---------------------------------------------------------------------------
__global__ __launch_bounds__(256) void emit_kernel(
    const unsigned short* __restrict__ keyW, const unsigned* __restrict__ selP,
    const float* __restrict__ thrp, float* __restrict__ outF)
{
    long long idx = OFF_E + (long long)blockIdx.x * 256 + threadIdx.x;
    if (idx >= TOT) return;

    if (idx < OFF_B) {                       // edge_index
        long long q = idx - OFF_E;
        int row = (int)(q / B2K);
        int rem = (int)(q - (long long)row * B2K);
        int b = rem / (2 * KSEL);
        int t = rem - b * (2 * KSEL);
        int slot = (t < KSEL) ? t : (t - KSEL);
        unsigned p = selP[(size_t)b * KSEL + slot];
        if (p >= PRECT) p = 1;
        int i = p / NN;
        int j = p - i * NN;
        bool first = (t < KSEL);
        int node = (row == 0) ? (first ? i : j) : (first ? j : i);
        outF[idx] = (float)(b * NN + node);
        return;
    }
    if (idx < OFF_P) {                       // batch
        int m = (int)(idx - OFF_B);
        outF[idx] = (float)(m / NN);
        return;
    }
    {                                        // top_probs
        int m = (int)(idx - OFF_P);
        int b = m / KSEL;
        int k = m - b * KSEL;
        unsigned p = selP[(size_t)b * KSEL + k];
        if (p >= PRECT) p = 1;
        unsigned short key = keyW[(size_t)b * PRECT + p];
        float d2 = __uint_as_float(((unsigned)key) << 16);
        float dist = sqrtf(fmaxf(d2, 1e-12f));
        outF[idx] = 1.0f / (1.0f + expf(dist - thrp[0]));
    }
}

// ---------------------------------------------------------------------------
extern "C" void kernel_launch(void* const* d_in, const int* in_sizes, int n_in,
                              void* d_out, int out_size, void* d_ws, size_t ws_size,
                              hipStream_t stream) {
    (void)in_sizes; (void)n_in; (void)out_size; (void)ws_size;
    const float* z   = (const float*)d_in[0];
    const int*   cls = (const int*)d_in[1];
    const float* et  = (const float*)d_in[2];
    const float* W1  = (const float*)d_in[3];
    const float* b1  = (const float*)d_in[4];
    const float* W2  = (const float*)d_in[5];
    const float* b2  = (const float*)d_in[6];
    const float* We  = (const float*)d_in[7];
    const float* be  = (const float*)d_in[8];
    const float* thr = (const float*)d_in[9];
    float* outF = (float*)d_out;

    char* w = (char*)d_ws;
    short*          hW   = (short*)(w + WS_H);
    float*          sqW  = (float*)(w + WS_SQ);
    short*          W1p  = (short*)(w + WS_W1P);
    short*          W2p  = (short*)(w + WS_W2P);
    short*          Wep  = (short*)(w + WS_WEP);
    short*          t1   = (short*)(w + WS_T1);
    unsigned short* keyW = (unsigned short*)(w + WS_KEY);
    unsigned*       selP = (unsigned*)(w + WS_SEL);

    pack_all_kernel<<<1504, 256, 0, stream>>>(W1, W2, We, W1p, W2p, Wep, sqW);

    for (int h = 0; h < 2; ++h) {
        int aBase = h * 12288;
        gemm_t<1><<<dim3(96, 4), 256, 0, stream>>>(
            nullptr, z, cls, et, W1p, b1, nullptr, t1, nullptr, 192, 512, 1, aBase);
        gemm_t<0><<<dim3(96, 2), 256, 0, stream>>>(
            t1, nullptr, nullptr, nullptr, W2p, b2, outF + OFF_X, nullptr, nullptr,
            512, 256, 0, aBase);
    }
    gemm_t<2><<<dim3(192, 4), 256, 0, stream>>>(
        nullptr, outF + OFF_X, nullptr, nullptr, Wep, be, nullptr, hW, sqW,
        256, 512, 1, 0);

    gram_mfma_kernel<<<dim3(64, 21), 256, 34816, stream>>>(hW, sqW, keyW);
    select_kernel<<<64, 1024, 0, stream>>>(keyW, selP);
    int emitN = TOT - OFF_E;
    emit_kernel<<<(emitN + 255) / 256, 256, 0, stream>>>(keyW, selP, thr, outF);
}

// Round 14
// 277.562 us; speedup vs baseline: 2.0203x; 1.3283x over previous
//
#include <hip/hip_runtime.h>
#include <hip/hip_bf16.h>

// Problem constants (match reference)
#define NB    64
#define NN    384
#define PPAIR 73536     // NN*(NN-1)/2 (reference pair count)
#define PRECT 147456    // NN*NN rectangular key space
#define KSEL  3677      // round(0.05 * PPAIR)
#define NSLICE 8
#define SLICEK (PRECT / NSLICE)   // 18432

// d_out layout (FLOAT32 elements, concatenated in return order)
#define OFF_X 0
#define OFF_E 6291456
#define B2K   470656    // NB*2*KSEL
#define OFF_B 7232768
#define OFF_P 7257344
#define TOT   7492672

// ws layout (45.8 MB peak, within proven 48.1 MB bound)
// NOTE: ghist/sliceBase alias the h region — h is dead once gram completes.
#define WS_H     0ull          // h bf16: 24576*512*2        = 25165824
#define WS_GH    0ull          // ghist u32: 64*8*4096*4     = 8388608 (after gram)
#define WS_SB    8388608ull    // sliceBase u32: 8388608     (after gram)
#define WS_SQ    25165824ull   // sq f32: 24576*4            = 98304
#define WS_W1P   25264128ull   // W1 packed: 192*512*2       = 196608
#define WS_W2P   25460736ull   // W2 packed: 512*256*2       = 262144
#define WS_WEP   25722880ull   // We packed: 256*512*2       = 262144
#define WS_T1    25985024ull   // t1 half-M bf16: 12582912 (dead after GEMM2)
#define WS_KEY   25985024ull   // keys u16 rect alias t1: 18874368
#define WS_SEL   44859392ull   // selP u32: 64*3677*4        = 941312
#define WS_TB    45800704ull   // Tbuf u32: 64*4             = 256

typedef __attribute__((ext_vector_type(8))) short bf16x8;
typedef __attribute__((ext_vector_type(4))) float f32x4;

__device__ __forceinline__ short f2bf(float f) {
    __hip_bfloat16 h = __float2bfloat16(f);
    return *reinterpret_cast<short*>(&h);
}
__device__ __forceinline__ float bfs2f(unsigned s) {
    return __uint_as_float((s & 0xFFFFu) << 16);
}

// LDS-only barrier: waits own LDS ops, does NOT drain vmcnt.
__device__ __forceinline__ void bar_lds() {
    asm volatile("s_waitcnt lgkmcnt(0)\n\ts_barrier" ::: "memory");
}

// ---------------------------------------------------------------------------
// Fused pack: W1/W2/We f32 -> A-operand fragments of W^T (bf16), + zero sqW.
// ---------------------------------------------------------------------------
__device__ __forceinline__ void packOne(
    const float* __restrict__ W, int K, int N, short* __restrict__ dst, int idx)
{
    if (idx >= K * N) return;
    int j = idx & 7;
    int l = (idx >> 3) & 63;
    int rest = idx >> 9;
    int Kt = K >> 5;
    int kt = rest % Kt, mt = rest / Kt;
    int k = kt * 32 + (l >> 4) * 8 + j;
    int n = mt * 16 + (l & 15);
    dst[idx] = f2bf(W[(size_t)k * N + n]);
}

__global__ __launch_bounds__(256) void pack_all_kernel(
    const float* __restrict__ W1, const float* __restrict__ W2,
    const float* __restrict__ We, short* __restrict__ W1p,
    short* __restrict__ W2p, short* __restrict__ Wep, float* __restrict__ sqW)
{
    int blk = blockIdx.x, tid = threadIdx.x;
    if (blk < 384)        packOne(W1, 192, 512, W1p, blk * 256 + tid);
    else if (blk < 896)   packOne(W2, 512, 256, W2p, (blk - 384) * 256 + tid);
    else if (blk < 1408)  packOne(We, 256, 512, Wep, (blk - 896) * 256 + tid);
    else {
        int i = (blk - 1408) * 256 + tid;
        if (i < NB * NN) sqW[i] = 0.f;     // re-zeroed EVERY call (ws poisoned)
    }
}

// ---------------------------------------------------------------------------
// Templated tiled MFMA GEMM (unchanged from round 9).
// ---------------------------------------------------------------------------
template<int MODE>
__global__ __launch_bounds__(256) void gemm_t(
    const short* __restrict__ Ab, const float* __restrict__ Af,
    const int* __restrict__ cls, const float* __restrict__ et,
    const short* __restrict__ Wp, const float* __restrict__ bias,
    float* __restrict__ oF, short* __restrict__ oB, float* __restrict__ sqOut,
    int K, int N, int relu, int aBase)
{
    __shared__ short sA[128 * 72];
    const int tid = threadIdx.x;
    const int r0 = blockIdx.x * 128;
    const int f0 = blockIdx.y * 128;
    const int lane = tid & 63;
    const int l15 = lane & 15, kj = lane >> 4;
    const int aHalf = (tid >> 6) >> 1;
    const int bHalf = (tid >> 6) & 1;
    const int Kt = K >> 5;

    f32x4 acc[4][4];
#pragma unroll
    for (int t = 0; t < 4; ++t)
#pragma unroll
        for (int s = 0; s < 4; ++s) acc[t][s] = (f32x4){0.f, 0.f, 0.f, 0.f};

    int cl = (MODE == 1) ? cls[(aBase + r0) / NN] : 0;
    const int nKC = K >> 6;

    int4  rI[4];
    float4 rA[4], rB[4];

    auto issueLoads = [&](int kc) {
#pragma unroll
        for (int q = 0; q < 4; ++q) {
            int e = tid + (q << 8);
            int row = e >> 3, c8 = e & 7;
            int col = (kc << 6) + (c8 << 3);
            if (MODE == 0) {
                rI[q] = *(const int4*)(Ab + (size_t)(r0 + row) * K + col);
            } else if (MODE == 1) {
                if (col < 128) {
                    const float* src = Af + (size_t)(aBase + r0 + row) * 128 + col;
                    rA[q] = *(const float4*)src; rB[q] = *(const float4*)(src + 4);
                } else {
                    const float* src = et + cl * 64 + (col - 128);
                    rA[q] = *(const float4*)src; rB[q] = *(const float4*)(src + 4);
                }
            } else {
                const float* src = Af + (size_t)(r0 + row) * 256 + col;
                rA[q] = *(const float4*)src; rB[q] = *(const float4*)(src + 4);
            }
        }
    };
    auto storeStage = [&]() {
#pragma unroll
        for (int q = 0; q < 4; ++q) {
            int e = tid + (q << 8);
            int row = e >> 3, c8 = e & 7;
            int4 v;
            if (MODE == 0) {
                v = rI[q];
            } else {
                v.x = (unsigned short)f2bf(rA[q].x) | ((unsigned)(unsigned short)f2bf(rA[q].y) << 16);
                v.y = (unsigned short)f2bf(rA[q].z) | ((unsigned)(unsigned short)f2bf(rA[q].w) << 16);
                v.z = (unsigned short)f2bf(rB[q].x) | ((unsigned)(unsigned short)f2bf(rB[q].y) << 16);
                v.w = (unsigned short)f2bf(rB[q].z) | ((unsigned)(unsigned short)f2bf(rB[q].w) << 16);
            }
            *(int4*)(sA + row * 72 + (c8 << 3)) = v;
        }
    };

    issueLoads(0);
    for (int kc = 0; kc < nKC; ++kc) {
        storeStage();
        if (kc + 1 < nKC) issueLoads(kc + 1);
        bar_lds();
#pragma unroll
        for (int kt2 = 0; kt2 < 2; ++kt2) {
            int kt = (kc << 1) + kt2;
            bf16x8 aF[4], bF[4];
#pragma unroll
            for (int t = 0; t < 4; ++t) {
                int mt = (f0 >> 4) + aHalf * 4 + t;
                aF[t] = *(const bf16x8*)(Wp + ((size_t)(mt * Kt + kt) << 9) + (lane << 3));
            }
#pragma unroll
            for (int s = 0; s < 4; ++s)
                bF[s] = *(const bf16x8*)(sA + (bHalf * 64 + s * 16 + l15) * 72 + kt2 * 32 + (kj << 3));
#pragma unroll
            for (int t = 0; t < 4; ++t)
#pragma unroll
                for (int s = 0; s < 4; ++s)
                    acc[t][s] = __builtin_amdgcn_mfma_f32_16x16x32_bf16(aF[t], bF[s], acc[t][s], 0, 0, 0);
        }
        bar_lds();
    }

    float sqp[4] = {0.f, 0.f, 0.f, 0.f};
#pragma unroll
    for (int t = 0; t < 4; ++t) {
        int featBase = f0 + (aHalf * 4 + t) * 16 + (kj << 2);
        float4 bv = *(const float4*)(bias + featBase);
#pragma unroll
        for (int s = 0; s < 4; ++s) {
            int node = r0 + bHalf * 64 + s * 16 + l15;
            f32x4 a = acc[t][s];
            float v0 = a.x + bv.x, v1 = a.y + bv.y, v2 = a.z + bv.z, v3 = a.w + bv.w;
            if (relu) {
                v0 = fmaxf(v0, 0.f); v1 = fmaxf(v1, 0.f);
                v2 = fmaxf(v2, 0.f); v3 = fmaxf(v3, 0.f);
            }
            if (oF) {
                float4 o; o.x = v0; o.y = v1; o.z = v2; o.w = v3;
                *(float4*)(oF + (size_t)(aBase + node) * N + featBase) = o;
            }
            if (oB) {
                short s0 = f2bf(v0), s1 = f2bf(v1), s2 = f2bf(v2), s3 = f2bf(v3);
                int2 pk;
                pk.x = (unsigned short)s0 | ((unsigned)(unsigned short)s1 << 16);
                pk.y = (unsigned short)s2 | ((unsigned)(unsigned short)s3 << 16);
                *(int2*)(oB + (size_t)node * N + featBase) = pk;
                if (sqOut) {
                    float h0 = bfs2f((unsigned short)s0), h1 = bfs2f((unsigned short)s1);
                    float h2 = bfs2f((unsigned short)s2), h3 = bfs2f((unsigned short)s3);
                    sqp[s] += h0 * h0 + h1 * h1 + h2 * h2 + h3 * h3;
                }
            }
        }
    }
    if (oB && sqOut) {
#pragma unroll
        for (int s = 0; s < 4; ++s) {
            float v = sqp[s];
            v += __shfl_xor(v, 16);
            v += __shfl_xor(v, 32);
            if (kj == 0)
                atomicAdd(sqOut + aBase + r0 + bHalf * 64 + s * 16 + l15, v);
        }
    }
}

// ---------------------------------------------------------------------------
// MFMA gram -> d2 -> u16 keys into RECTANGULAR layout key[b][gi][384].
// Grid dim3(64 graphs, 21 tile-pairs) -> graph b's blocks share XCD b%8.
// Lower-half rect cells stay poison (key>=0x8000 -> never selected).
// ---------------------------------------------------------------------------
__global__ __launch_bounds__(256) void gram_mfma_kernel(
    const short* __restrict__ hW, const float* __restrict__ sqW,
    unsigned short* __restrict__ keyW)
{
    extern __shared__ short smem[];
    short* As = smem;            // [64][136]
    short* Bs = smem + 8704;     // [64][136]

    const int tid = threadIdx.x;
    const int b  = blockIdx.x;
    int tp = blockIdx.y;
    int ti = 0; { int rem = tp; while (rem >= 6 - ti) { rem -= 6 - ti; ++ti; } tp = rem; }
    const int tj = ti + tp;
    const bool diag = (ti == tj);
    const short* Bp = diag ? As : Bs;

    const int w = tid >> 6;
    const int lane = tid & 63;
    const int l15 = lane & 15, kj = lane >> 4;
    const int mb = w * 16;

    f32x4 acc[4];
#pragma unroll
    for (int t = 0; t < 4; ++t) acc[t] = (f32x4){0.f, 0.f, 0.f, 0.f};

    const size_t baseA = ((size_t)b * NN + ti * 64) * 512;
    const size_t baseB = ((size_t)b * NN + tj * 64) * 512;

    int4 pa[4], pb[4];
    auto issue = [&](int kc) {
#pragma unroll
        for (int q = 0; q < 4; ++q) {
            int i = tid + (q << 8);
            int row = i >> 4, g = i & 15;
            pa[q] = *(const int4*)(hW + baseA + row * 512 + kc * 128 + g * 8);
            if (!diag)
                pb[q] = *(const int4*)(hW + baseB + row * 512 + kc * 128 + g * 8);
        }
    };
    auto store = [&]() {
#pragma unroll
        for (int q = 0; q < 4; ++q) {
            int i = tid + (q << 8);
            int row = i >> 4, g = i & 15;
            *(int4*)(As + row * 136 + g * 8) = pa[q];
            if (!diag) *(int4*)(Bs + row * 136 + g * 8) = pb[q];
        }
    };

    issue(0);
    for (int kc = 0; kc < 4; ++kc) {
        store();
        if (kc < 3) issue(kc + 1);
        bar_lds();
#pragma unroll
        for (int kt = 0; kt < 4; ++kt) {
            bf16x8 aF = *(const bf16x8*)(As + (mb + l15) * 136 + kt * 32 + kj * 8);
#pragma unroll
            for (int nt = 0; nt < 4; ++nt) {
                bf16x8 bF = *(const bf16x8*)(Bp + (nt * 16 + l15) * 136 + kt * 32 + kj * 8);
                acc[nt] = __builtin_amdgcn_mfma_f32_16x16x32_bf16(aF, bF, acc[nt], 0, 0, 0);
            }
        }
        bar_lds();
    }

    // ---- epilogue: keys -> LDS u16 tile [64][72] -> coalesced row writes ----
    unsigned short* tile = (unsigned short*)smem;   // reuse As region
    float4 sqi = *(const float4*)(sqW + b * NN + ti * 64 + mb + kj * 4);
    float si[4] = { sqi.x, sqi.y, sqi.z, sqi.w };
#pragma unroll
    for (int nt = 0; nt < 4; ++nt) {
        int colL = nt * 16 + l15;
        float sj = sqW[b * NN + tj * 64 + colL];
        float av[4] = { acc[nt].x, acc[nt].y, acc[nt].z, acc[nt].w };
#pragma unroll
        for (int r = 0; r < 4; ++r) {
            int rowL = mb + kj * 4 + r;
            float d2 = fmaxf(si[r] + sj - 2.f * av[r], 0.f);
            unsigned short key = (unsigned short)(__float_as_uint(d2) >> 16);
            bool valid = !diag || (rowL < colL);
            tile[rowL * 72 + colL] = valid ? key : (unsigned short)0xFFFF;
        }
    }
    bar_lds();
#pragma unroll
    for (int it = 0; it < 2; ++it) {
        int idx = tid + (it << 8);          // 0..511
        int row = idx >> 3, c8 = idx & 7;
        int4 v = *(const int4*)(tile + row * 72 + c8 * 8);
        *(int4*)(keyW + (size_t)b * PRECT + (size_t)(ti * 64 + row) * NN
                 + tj * 64 + c8 * 8) = v;
    }
}

// ---------------------------------------------------------------------------
// Select v5 — sliced (8x parallelism), bin-ordered counting scatter.
// selA: per-slice LDS histogram -> ghist[b][s][4096] (stores, no glob atomics)
// selB: per-graph: total, scan, threshold bin T, sliceBase = base + slice-prefix
// selC: per-slice scatter via LDS counters initialized from sliceBase.
// Output positions ordered by (bin, slice, intra) -> same bin-ascending
// guarantee as the passing r8/r11 scheme.
// ---------------------------------------------------------------------------
__global__ __launch_bounds__(1024) void selA_kernel(
    const unsigned short* __restrict__ keyW, unsigned* __restrict__ ghist)
{
    const int b = blockIdx.x, s = blockIdx.y, tid = threadIdx.x;
    const unsigned short* keys = keyW + (size_t)b * PRECT + (size_t)s * SLICEK;
    __shared__ unsigned hist[4096];
    for (int i = tid; i < 4096; i += 1024) hist[i] = 0;
    __syncthreads();
    for (int p = tid; p < SLICEK; p += 1024) {
        unsigned k = keys[p];
        if (k < 0x8000u) atomicAdd(&hist[k >> 4], 1u);
    }
    __syncthreads();
    unsigned* dst = ghist + ((size_t)(b * NSLICE + s) << 12);
    for (int i = tid; i < 4096; i += 1024) dst[i] = hist[i];
}

__global__ __launch_bounds__(1024) void selB_kernel(
    const unsigned* __restrict__ ghist, unsigned* __restrict__ sliceBase,
    unsigned* __restrict__ Tbuf)
{
    const int b = blockIdx.x, tid = threadIdx.x;
    __shared__ unsigned base[4096];
    __shared__ unsigned scanBuf[1024];
    __shared__ int sTc;
    if (tid == 0) sTc = 4095;

    unsigned c[4]; unsigned tsum = 0;
#pragma unroll
    for (int q = 0; q < 4; ++q) {
        int bin = tid * 4 + q;
        unsigned v = 0;
        for (int s = 0; s < NSLICE; ++s)
            v += ghist[((size_t)(b * NSLICE + s) << 12) + bin];
        c[q] = v; tsum += v;
    }
    scanBuf[tid] = tsum;
    __syncthreads();
    for (int o = 1; o < 1024; o <<= 1) {
        unsigned v = (tid >= o) ? scanBuf[tid - o] : 0u;
        __syncthreads();
        scanBuf[tid] += v;
        __syncthreads();
    }
    unsigned exc = scanBuf[tid] - tsum;
    {
        unsigned run = exc;
#pragma unroll
        for (int q = 0; q < 4; ++q) { base[tid * 4 + q] = run; run += c[q]; }
    }
    __syncthreads();
#pragma unroll
    for (int q = 0; q < 4; ++q) {
        int i = tid * 4 + q;
        if (base[i] < KSEL && base[i] + c[q] >= KSEL) atomicMin(&sTc, i);
    }
    __syncthreads();
    if (tid == 0) Tbuf[b] = (unsigned)sTc;

    // sliceBase[b][s][bin] = base[bin] + sum_{s'<s} ghist[b][s'][bin]
#pragma unroll
    for (int q = 0; q < 4; ++q) {
        int bin = tid * 4 + q;
        unsigned runb = base[bin];
        for (int s = 0; s < NSLICE; ++s) {
            size_t off = ((size_t)(b * NSLICE + s) << 12) + bin;
            sliceBase[off] = runb;
            runb += ghist[off];
        }
    }
}

__global__ __launch_bounds__(1024) void selC_kernel(
    const unsigned short* __restrict__ keyW, const unsigned* __restrict__ sliceBase,
    const unsigned* __restrict__ Tbuf, unsigned* __restrict__ selP)
{
    const int b = blockIdx.x, s = blockIdx.y, tid = threadIdx.x;
    const unsigned short* keys = keyW + (size_t)b * PRECT + (size_t)s * SLICEK;
    __shared__ unsigned cnt[4096];
    const unsigned* src = sliceBase + ((size_t)(b * NSLICE + s) << 12);
    for (int i = tid; i < 4096; i += 1024) cnt[i] = src[i];
    __syncthreads();
    int T = (int)Tbuf[b];
    for (int p = tid; p < SLICEK; p += 1024) {
        unsigned k = keys[p];
        if (k < 0x8000u) {
            int bin = k >> 4;
            if (bin <= T) {
                unsigned pos = atomicAdd(&cnt[bin], 1u);
                if (pos < KSEL)
                    selP[(size_t)b * KSEL + pos] = (unsigned)(s * SLICEK + p);
            }
        }
    }
}

// ---------------------------------------------------------------------------
// emit edge_index, batch, top_probs as FLOAT32 ([OFF_E, TOT)).
// Rect pair decode: i = p/384, j = p%384.
// ---------------------------------------------------------------------------
__global__ __launch_bounds__(256) void emit_kernel(
    const unsigned short* __restrict__ keyW, const unsigned* __restrict__ selP,
    const float* __restrict__ thrp, float* __restrict__ outF)
{
    long long idx = OFF_E + (long long)blockIdx.x * 256 + threadIdx.x;
    if (idx >= TOT) return;

    if (idx < OFF_B) {                       // edge_index
        long long q = idx - OFF_E;
        int row = (int)(q / B2K);
        int rem = (int)(q - (long long)row * B2K);
        int b = rem / (2 * KSEL);
        int t = rem - b * (2 * KSEL);
        int slot = (t < KSEL) ? t : (t - KSEL);
        unsigned p = selP[(size_t)b * KSEL + slot];
        if (p >= PRECT) p = 1;
        int i = p / NN;
        int j = p - i * NN;
        bool first = (t < KSEL);
        int node = (row == 0) ? (first ? i : j) : (first ? j : i);
        outF[idx] = (float)(b * NN + node);
        return;
    }
    if (idx < OFF_P) {                       // batch
        int m = (int)(idx - OFF_B);
        outF[idx] = (float)(m / NN);
        return;
    }
    {                                        // top_probs
        int m = (int)(idx - OFF_P);
        int b = m / KSEL;
        int k = m - b * KSEL;
        unsigned p = selP[(size_t)b * KSEL + k];
        if (p >= PRECT) p = 1;
        unsigned short key = keyW[(size_t)b * PRECT + p];
        float d2 = __uint_as_float(((unsigned)key) << 16);
        float dist = sqrtf(fmaxf(d2, 1e-12f));
        outF[idx] = 1.0f / (1.0f + expf(dist - thrp[0]));
    }
}

// ---------------------------------------------------------------------------
extern "C" void kernel_launch(void* const* d_in, const int* in_sizes, int n_in,
                              void* d_out, int out_size, void* d_ws, size_t ws_size,
                              hipStream_t stream) {
    (void)in_sizes; (void)n_in; (void)out_size; (void)ws_size;
    const float* z   = (const float*)d_in[0];
    const int*   cls = (const int*)d_in[1];
    const float* et  = (const float*)d_in[2];
    const float* W1  = (const float*)d_in[3];
    const float* b1  = (const float*)d_in[4];
    const float* W2  = (const float*)d_in[5];
    const float* b2  = (const float*)d_in[6];
    const float* We  = (const float*)d_in[7];
    const float* be  = (const float*)d_in[8];
    const float* thr = (const float*)d_in[9];
    float* outF = (float*)d_out;

    char* w = (char*)d_ws;
    short*          hW    = (short*)(w + WS_H);
    float*          sqW   = (float*)(w + WS_SQ);
    short*          W1p   = (short*)(w + WS_W1P);
    short*          W2p   = (short*)(w + WS_W2P);
    short*          Wep   = (short*)(w + WS_WEP);
    short*          t1    = (short*)(w + WS_T1);
    unsigned short* keyW  = (unsigned short*)(w + WS_KEY);
    unsigned*       selP  = (unsigned*)(w + WS_SEL);
    unsigned*       ghist = (unsigned*)(w + WS_GH);   // aliases dead hW
    unsigned*       sbase = (unsigned*)(w + WS_SB);   // aliases dead hW
    unsigned*       Tbuf  = (unsigned*)(w + WS_TB);

    pack_all_kernel<<<1504, 256, 0, stream>>>(W1, W2, We, W1p, W2p, Wep, sqW);

    for (int h = 0; h < 2; ++h) {
        int aBase = h * 12288;
        gemm_t<1><<<dim3(96, 4), 256, 0, stream>>>(
            nullptr, z, cls, et, W1p, b1, nullptr, t1, nullptr, 192, 512, 1, aBase);
        gemm_t<0><<<dim3(96, 2), 256, 0, stream>>>(
            t1, nullptr, nullptr, nullptr, W2p, b2, outF + OFF_X, nullptr, nullptr,
            512, 256, 0, aBase);
    }
    gemm_t<2><<<dim3(192, 4), 256, 0, stream>>>(
        nullptr, outF + OFF_X, nullptr, nullptr, Wep, be, nullptr, hW, sqW,
        256, 512, 1, 0);

    gram_mfma_kernel<<<dim3(64, 21), 256, 34816, stream>>>(hW, sqW, keyW);
    selA_kernel<<<dim3(64, NSLICE), 1024, 0, stream>>>(keyW, ghist);
    selB_kernel<<<64, 1024, 0, stream>>>(ghist, sbase, Tbuf);
    selC_kernel<<<dim3(64, NSLICE), 1024, 0, stream>>>(keyW, sbase, Tbuf, selP);
    int emitN = TOT - OFF_E;
    emit_kernel<<<(emitN + 255) / 256, 256, 0, stream>>>(keyW, selP, thr, outF);
}

// Round 15
// 235.193 us; speedup vs baseline: 2.3842x; 1.1801x over previous
//
#include <hip/hip_runtime.h>
#include <hip/hip_bf16.h>

// Problem constants (match reference)
#define NB    64
#define NN    384
#define PPAIR 73536     // NN*(NN-1)/2 (reference pair count)
#define PRECT 147456    // NN*NN rectangular key space
#define KSEL  3677      // round(0.05 * PPAIR)
#define NSLICE 8
#define SLICEK (PRECT / NSLICE)   // 18432

// d_out layout (FLOAT32 elements, concatenated in return order)
#define OFF_X 0
#define OFF_E 6291456
#define B2K   470656    // NB*2*KSEL
#define OFF_B 7232768
#define OFF_P 7257344
#define TOT   7492672

// ws layout (39.5 MB peak, within proven 48.1 MB bound)
#define WS_H8    0ull          // h fp8: 24576*512           = 12582912
#define WS_GH    0ull          // ghist u16: 64*8*4096*2     = 4194304  (alias h, post-gram)
#define WS_SB    4194304ull    // sliceBase u32: 64*8*4096*4 = 8388608  (alias h, ends 12582912)
#define WS_SQ    12582912ull   // sq f32: 24576*4            = 98304
#define WS_W1P   12681216ull   // W1 packed bf16: 192*512*2  = 196608
#define WS_W2P   12877824ull   // W2 packed bf16: 512*256*2  = 262144
#define WS_WEP   13139968ull   // We packed bf16: 256*512*2  = 262144
#define WS_T1    13402112ull   // t1 bf16 FULL-M: 24576*512*2 = 25165824 (dead after GEMM2)
#define WS_KEY   13402112ull   // keys u16 rect alias t1: 18874368 (ends 32276480)
#define WS_SEL   38567936ull   // selP u32: 64*3677*4        = 941312
#define WS_TB    39509248ull   // Tbuf u32: 64*4             = 256

typedef __attribute__((ext_vector_type(8))) short bf16x8;
typedef __attribute__((ext_vector_type(4))) float f32x4;

__device__ __forceinline__ short f2bf(float f) {
    __hip_bfloat16 h = __float2bfloat16(f);
    return *reinterpret_cast<short*>(&h);
}
__device__ __forceinline__ float bfs2f(unsigned s) {
    return __uint_as_float((s & 0xFFFFu) << 16);
}
// fp8 e4m3fn codec (positive values only; h >= 0 after relu)
__device__ __forceinline__ unsigned enc8(float h) {
    if (!(h > 0.0078125f)) return 0u;                 // flush tiny/zero/neg
    unsigned u = __float_as_uint(h) + 0x00080000u;    // round mantissa to 3 bits
    int E = (int)(u >> 23) - 127;
    if (E > 8)  return 0x7Eu;                         // clamp to 448 (avoid NaN 0x7F)
    if (E < -6) return 0u;
    return (unsigned)(((E + 7) << 3) | ((u >> 20) & 7u));
}
__device__ __forceinline__ float dec8(unsigned b) {
    if (b == 0u) return 0.f;
    return __uint_as_float((((b >> 3) + 120u) << 23) | ((b & 7u) << 20));
}

// LDS-only barrier: waits own LDS ops, does NOT drain vmcnt.
__device__ __forceinline__ void bar_lds() {
    asm volatile("s_waitcnt lgkmcnt(0)\n\ts_barrier" ::: "memory");
}

// ---------------------------------------------------------------------------
// Fused pack: W1/W2/We f32 -> A-operand fragments of W^T (bf16), + zero sqW.
// ---------------------------------------------------------------------------
__device__ __forceinline__ void packOne(
    const float* __restrict__ W, int K, int N, short* __restrict__ dst, int idx)
{
    if (idx >= K * N) return;
    int j = idx & 7;
    int l = (idx >> 3) & 63;
    int rest = idx >> 9;
    int Kt = K >> 5;
    int kt = rest % Kt, mt = rest / Kt;
    int k = kt * 32 + (l >> 4) * 8 + j;
    int n = mt * 16 + (l & 15);
    dst[idx] = f2bf(W[(size_t)k * N + n]);
}

__global__ __launch_bounds__(256) void pack_all_kernel(
    const float* __restrict__ W1, const float* __restrict__ W2,
    const float* __restrict__ We, short* __restrict__ W1p,
    short* __restrict__ W2p, short* __restrict__ Wep, float* __restrict__ sqW)
{
    int blk = blockIdx.x, tid = threadIdx.x;
    if (blk < 384)        packOne(W1, 192, 512, W1p, blk * 256 + tid);
    else if (blk < 896)   packOne(W2, 512, 256, W2p, (blk - 384) * 256 + tid);
    else if (blk < 1408)  packOne(We, 256, 512, Wep, (blk - 896) * 256 + tid);
    else {
        int i = (blk - 1408) * 256 + tid;
        if (i < NB * NN) sqW[i] = 0.f;     // re-zeroed EVERY call (ws poisoned)
    }
}

// ---------------------------------------------------------------------------
// Templated tiled MFMA GEMM. MODE: 0 = A bf16, 1 = [z|ce] f32, 2 = A f32.
// OUT8: bf16-out (0) or fp8-out + sq (1).
// ---------------------------------------------------------------------------
template<int MODE, int OUT8>
__global__ __launch_bounds__(256) void gemm_t(
    const short* __restrict__ Ab, const float* __restrict__ Af,
    const int* __restrict__ cls, const float* __restrict__ et,
    const short* __restrict__ Wp, const float* __restrict__ bias,
    float* __restrict__ oF, void* __restrict__ oB, float* __restrict__ sqOut,
    int K, int N, int relu)
{
    __shared__ short sA[128 * 72];
    const int tid = threadIdx.x;
    const int r0 = blockIdx.x * 128;
    const int f0 = blockIdx.y * 128;
    const int lane = tid & 63;
    const int l15 = lane & 15, kj = lane >> 4;
    const int aHalf = (tid >> 6) >> 1;
    const int bHalf = (tid >> 6) & 1;
    const int Kt = K >> 5;

    f32x4 acc[4][4];
#pragma unroll
    for (int t = 0; t < 4; ++t)
#pragma unroll
        for (int s = 0; s < 4; ++s) acc[t][s] = (f32x4){0.f, 0.f, 0.f, 0.f};

    int cl = (MODE == 1) ? cls[r0 / NN] : 0;
    const int nKC = K >> 6;

    int4  rI[4];
    float4 rA[4], rB[4];

    auto issueLoads = [&](int kc) {
#pragma unroll
        for (int q = 0; q < 4; ++q) {
            int e = tid + (q << 8);
            int row = e >> 3, c8 = e & 7;
            int col = (kc << 6) + (c8 << 3);
            if (MODE == 0) {
                rI[q] = *(const int4*)(Ab + (size_t)(r0 + row) * K + col);
            } else if (MODE == 1) {
                if (col < 128) {
                    const float* src = Af + (size_t)(r0 + row) * 128 + col;
                    rA[q] = *(const float4*)src; rB[q] = *(const float4*)(src + 4);
                } else {
                    const float* src = et + cl * 64 + (col - 128);
                    rA[q] = *(const float4*)src; rB[q] = *(const float4*)(src + 4);
                }
            } else {
                const float* src = Af + (size_t)(r0 + row) * 256 + col;
                rA[q] = *(const float4*)src; rB[q] = *(const float4*)(src + 4);
            }
        }
    };
    auto storeStage = [&]() {
#pragma unroll
        for (int q = 0; q < 4; ++q) {
            int e = tid + (q << 8);
            int row = e >> 3, c8 = e & 7;
            int4 v;
            if (MODE == 0) {
                v = rI[q];
            } else {
                v.x = (unsigned short)f2bf(rA[q].x) | ((unsigned)(unsigned short)f2bf(rA[q].y) << 16);
                v.y = (unsigned short)f2bf(rA[q].z) | ((unsigned)(unsigned short)f2bf(rA[q].w) << 16);
                v.z = (unsigned short)f2bf(rB[q].x) | ((unsigned)(unsigned short)f2bf(rB[q].y) << 16);
                v.w = (unsigned short)f2bf(rB[q].z) | ((unsigned)(unsigned short)f2bf(rB[q].w) << 16);
            }
            *(int4*)(sA + row * 72 + (c8 << 3)) = v;
        }
    };

    issueLoads(0);
    for (int kc = 0; kc < nKC; ++kc) {
        storeStage();
        if (kc + 1 < nKC) issueLoads(kc + 1);
        bar_lds();
#pragma unroll
        for (int kt2 = 0; kt2 < 2; ++kt2) {
            int kt = (kc << 1) + kt2;
            bf16x8 aF[4], bF[4];
#pragma unroll
            for (int t = 0; t < 4; ++t) {
                int mt = (f0 >> 4) + aHalf * 4 + t;
                aF[t] = *(const bf16x8*)(Wp + ((size_t)(mt * Kt + kt) << 9) + (lane << 3));
            }
#pragma unroll
            for (int s = 0; s < 4; ++s)
                bF[s] = *(const bf16x8*)(sA + (bHalf * 64 + s * 16 + l15) * 72 + kt2 * 32 + (kj << 3));
#pragma unroll
            for (int t = 0; t < 4; ++t)
#pragma unroll
                for (int s = 0; s < 4; ++s)
                    acc[t][s] = __builtin_amdgcn_mfma_f32_16x16x32_bf16(aF[t], bF[s], acc[t][s], 0, 0, 0);
        }
        bar_lds();
    }

    float sqp[4] = {0.f, 0.f, 0.f, 0.f};
#pragma unroll
    for (int t = 0; t < 4; ++t) {
        int featBase = f0 + (aHalf * 4 + t) * 16 + (kj << 2);
        float4 bv = *(const float4*)(bias + featBase);
#pragma unroll
        for (int s = 0; s < 4; ++s) {
            int node = r0 + bHalf * 64 + s * 16 + l15;
            f32x4 a = acc[t][s];
            float v0 = a.x + bv.x, v1 = a.y + bv.y, v2 = a.z + bv.z, v3 = a.w + bv.w;
            if (relu) {
                v0 = fmaxf(v0, 0.f); v1 = fmaxf(v1, 0.f);
                v2 = fmaxf(v2, 0.f); v3 = fmaxf(v3, 0.f);
            }
            if (oF) {
                float4 o; o.x = v0; o.y = v1; o.z = v2; o.w = v3;
                *(float4*)(oF + (size_t)node * N + featBase) = o;
            }
            if (oB) {
                if (OUT8) {
                    unsigned e0 = enc8(v0), e1 = enc8(v1), e2 = enc8(v2), e3 = enc8(v3);
                    *(unsigned*)((unsigned char*)oB + (size_t)node * N + featBase) =
                        e0 | (e1 << 8) | (e2 << 16) | (e3 << 24);
                    float h0 = dec8(e0), h1 = dec8(e1), h2 = dec8(e2), h3 = dec8(e3);
                    sqp[s] += h0 * h0 + h1 * h1 + h2 * h2 + h3 * h3;
                } else {
                    short s0 = f2bf(v0), s1 = f2bf(v1), s2 = f2bf(v2), s3 = f2bf(v3);
                    int2 pk;
                    pk.x = (unsigned short)s0 | ((unsigned)(unsigned short)s1 << 16);
                    pk.y = (unsigned short)s2 | ((unsigned)(unsigned short)s3 << 16);
                    *(int2*)((short*)oB + (size_t)node * N + featBase) = pk;
                }
            }
        }
    }
    if (OUT8 && sqOut) {
#pragma unroll
        for (int s = 0; s < 4; ++s) {
            float v = sqp[s];
            v += __shfl_xor(v, 16);
            v += __shfl_xor(v, 32);
            if (kj == 0)
                atomicAdd(sqOut + r0 + bHalf * 64 + s * 16 + l15, v);
        }
    }
}

// ---------------------------------------------------------------------------
// fp8 MFMA gram -> d2 -> u16 keys into RECTANGULAR layout key[b][gi][384].
// Grid dim3(64 graphs, 21 tile-pairs) -> graph b's blocks share XCD b%8.
// h is fp8 e4m3fn; mfma_f32_16x16x32_fp8_fp8 (8B operands/lane, same geometry
// as the verified bf16 16x16x32 mapping). Lower-half cells stay poison.
// ---------------------------------------------------------------------------
__global__ __launch_bounds__(256) void gram_mfma_kernel(
    const unsigned char* __restrict__ hW8, const float* __restrict__ sqW,
    unsigned short* __restrict__ keyW)
{
    extern __shared__ unsigned char smem8[];
    unsigned char* As = smem8;           // [64][264] fp8 (256 + 8 pad)
    unsigned char* Bs = smem8 + 16896;

    const int tid = threadIdx.x;
    const int b  = blockIdx.x;
    int tp = blockIdx.y;
    int ti = 0; { int rem = tp; while (rem >= 6 - ti) { rem -= 6 - ti; ++ti; } tp = rem; }
    const int tj = ti + tp;
    const bool diag = (ti == tj);
    const unsigned char* Bp = diag ? As : Bs;

    const int w = tid >> 6;
    const int lane = tid & 63;
    const int l15 = lane & 15, kj = lane >> 4;
    const int mb = w * 16;

    f32x4 acc[4];
#pragma unroll
    for (int t = 0; t < 4; ++t) acc[t] = (f32x4){0.f, 0.f, 0.f, 0.f};

    const size_t baseA = ((size_t)b * NN + ti * 64) * 512;   // bytes
    const size_t baseB = ((size_t)b * NN + tj * 64) * 512;

    int4 pa[4], pb[4];
    auto issue = [&](int kc) {
#pragma unroll
        for (int q = 0; q < 4; ++q) {
            int i = tid + (q << 8);          // 0..1023; row=i>>4, g=i&15 (16B each)
            int row = i >> 4, g = i & 15;
            pa[q] = *(const int4*)(hW8 + baseA + row * 512 + kc * 256 + g * 16);
            if (!diag)
                pb[q] = *(const int4*)(hW8 + baseB + row * 512 + kc * 256 + g * 16);
        }
    };
    auto store = [&]() {
#pragma unroll
        for (int q = 0; q < 4; ++q) {
            int i = tid + (q << 8);
            int row = i >> 4, g = i & 15;
            *(int4*)(As + row * 264 + g * 16) = pa[q];
            if (!diag) *(int4*)(Bs + row * 264 + g * 16) = pb[q];
        }
    };

    issue(0);
    for (int kc = 0; kc < 2; ++kc) {         // 2 chunks of 256 fp8
        store();
        if (kc == 0) issue(1);
        bar_lds();
#pragma unroll
        for (int kt = 0; kt < 8; ++kt) {     // 8 x K=32 steps per chunk
            long long aF = *(const long long*)(As + (mb + l15) * 264 + kt * 32 + kj * 8);
#pragma unroll
            for (int nt = 0; nt < 4; ++nt) {
                long long bF = *(const long long*)(Bp + (nt * 16 + l15) * 264 + kt * 32 + kj * 8);
                acc[nt] = __builtin_amdgcn_mfma_f32_16x16x32_fp8_fp8(aF, bF, acc[nt], 0, 0, 0);
            }
        }
        bar_lds();
    }

    // ---- epilogue: keys -> LDS u16 tile [64][72] -> coalesced row writes ----
    unsigned short* tile = (unsigned short*)smem8;   // reuse As region (9216 B)
    float4 sqi = *(const float4*)(sqW + b * NN + ti * 64 + mb + kj * 4);
    float si[4] = { sqi.x, sqi.y, sqi.z, sqi.w };
#pragma unroll
    for (int nt = 0; nt < 4; ++nt) {
        int colL = nt * 16 + l15;
        float sj = sqW[b * NN + tj * 64 + colL];
        float av[4] = { acc[nt].x, acc[nt].y, acc[nt].z, acc[nt].w };
#pragma unroll
        for (int r = 0; r < 4; ++r) {
            int rowL = mb + kj * 4 + r;
            float d2 = fmaxf(si[r] + sj - 2.f * av[r], 0.f);
            unsigned short key = (unsigned short)(__float_as_uint(d2) >> 16);
            bool valid = !diag || (rowL < colL);
            tile[rowL * 72 + colL] = valid ? key : (unsigned short)0xFFFF;
        }
    }
    bar_lds();
#pragma unroll
    for (int it = 0; it < 2; ++it) {
        int idx = tid + (it << 8);          // 0..511
        int row = idx >> 3, c8 = idx & 7;
        int4 v = *(const int4*)(tile + row * 72 + c8 * 8);
        *(int4*)(keyW + (size_t)b * PRECT + (size_t)(ti * 64 + row) * NN
                 + tj * 64 + c8 * 8) = v;
    }
}

// ---------------------------------------------------------------------------
// Select v5 — sliced (8x parallelism), bin-ordered counting scatter.
// ---------------------------------------------------------------------------
__global__ __launch_bounds__(1024) void selA_kernel(
    const unsigned short* __restrict__ keyW, unsigned short* __restrict__ ghist)
{
    const int b = blockIdx.x, s = blockIdx.y, tid = threadIdx.x;
    const unsigned short* keys = keyW + (size_t)b * PRECT + (size_t)s * SLICEK;
    __shared__ unsigned hist[4096];
    for (int i = tid; i < 4096; i += 1024) hist[i] = 0;
    __syncthreads();
    for (int p = tid; p < SLICEK; p += 1024) {
        unsigned k = keys[p];
        if (k < 0x8000u) atomicAdd(&hist[k >> 4], 1u);
    }
    __syncthreads();
    unsigned short* dst = ghist + ((size_t)(b * NSLICE + s) << 12);
    for (int i = tid; i < 4096; i += 1024) dst[i] = (unsigned short)hist[i];
}

__global__ __launch_bounds__(1024) void selB_kernel(
    const unsigned short* __restrict__ ghist, unsigned* __restrict__ sliceBase,
    unsigned* __restrict__ Tbuf)
{
    const int b = blockIdx.x, tid = threadIdx.x;
    __shared__ unsigned base[4096];
    __shared__ unsigned scanBuf[1024];
    __shared__ int sTc;
    if (tid == 0) sTc = 4095;

    unsigned c[4]; unsigned tsum = 0;
#pragma unroll
    for (int q = 0; q < 4; ++q) {
        int bin = tid * 4 + q;
        unsigned v = 0;
        for (int s = 0; s < NSLICE; ++s)
            v += ghist[((size_t)(b * NSLICE + s) << 12) + bin];
        c[q] = v; tsum += v;
    }
    scanBuf[tid] = tsum;
    __syncthreads();
    for (int o = 1; o < 1024; o <<= 1) {
        unsigned v = (tid >= o) ? scanBuf[tid - o] : 0u;
        __syncthreads();
        scanBuf[tid] += v;
        __syncthreads();
    }
    unsigned exc = scanBuf[tid] - tsum;
    {
        unsigned run = exc;
#pragma unroll
        for (int q = 0; q < 4; ++q) { base[tid * 4 + q] = run; run += c[q]; }
    }
    __syncthreads();
#pragma unroll
    for (int q = 0; q < 4; ++q) {
        int i = tid * 4 + q;
        if (base[i] < KSEL && base[i] + c[q] >= KSEL) atomicMin(&sTc, i);
    }
    __syncthreads();
    if (tid == 0) Tbuf[b] = (unsigned)sTc;

#pragma unroll
    for (int q = 0; q < 4; ++q) {
        int bin = tid * 4 + q;
        unsigned runb = base[bin];
        for (int s = 0; s < NSLICE; ++s) {
            size_t off = ((size_t)(b * NSLICE + s) << 12) + bin;
            sliceBase[off] = runb;
            runb += ghist[off];
        }
    }
}

__global__ __launch_bounds__(1024) void selC_kernel(
    const unsigned short* __restrict__ keyW, const unsigned* __restrict__ sliceBase,
    const unsigned* __restrict__ Tbuf, unsigned* __restrict__ selP)
{
    const int b = blockIdx.x, s = blockIdx.y, tid = threadIdx.x;
    const unsigned short* keys = keyW + (size_t)b * PRECT + (size_t)s * SLICEK;
    __shared__ unsigned cnt[4096];
    const unsigned* src = sliceBase + ((size_t)(b * NSLICE + s) << 12);
    for (int i = tid; i < 4096; i += 1024) cnt[i] = src[i];
    __syncthreads();
    int T = (int)Tbuf[b];
    for (int p = tid; p < SLICEK; p += 1024) {
        unsigned k = keys[p];
        if (k < 0x8000u) {
            int bin = k >> 4;
            if (bin <= T) {
                unsigned pos = atomicAdd(&cnt[bin], 1u);
                if (pos < KSEL)
                    selP[(size_t)b * KSEL + pos] = (unsigned)(s * SLICEK + p);
            }
        }
    }
}

// ---------------------------------------------------------------------------
// emit edge_index, batch, top_probs as FLOAT32 ([OFF_E, TOT)).
// ---------------------------------------------------------------------------
__global__ __launch_bounds__(256) void emit_kernel(
    const unsigned short* __restrict__ keyW, const unsigned* __restrict__ selP,
    const float* __restrict__ thrp, float* __restrict__ outF)
{
    long long idx = OFF_E + (long long)blockIdx.x * 256 + threadIdx.x;
    if (idx >= TOT) return;

    if (idx < OFF_B) {                       // edge_index
        long long q = idx - OFF_E;
        int row = (int)(q / B2K);
        int rem = (int)(q - (long long)row * B2K);
        int b = rem / (2 * KSEL);
        int t = rem - b * (2 * KSEL);
        int slot = (t < KSEL) ? t : (t - KSEL);
        unsigned p = selP[(size_t)b * KSEL + slot];
        if (p >= PRECT) p = 1;
        int i = p / NN;
        int j = p - i * NN;
        bool first = (t < KSEL);
        int node = (row == 0) ? (first ? i : j) : (first ? j : i);
        outF[idx] = (float)(b * NN + node);
        return;
    }
    if (idx < OFF_P) {                       // batch
        int m = (int)(idx - OFF_B);
        outF[idx] = (float)(m / NN);
        return;
    }
    {                                        // top_probs
        int m = (int)(idx - OFF_P);
        int b = m / KSEL;
        int k = m - b * KSEL;
        unsigned p = selP[(size_t)b * KSEL + k];
        if (p >= PRECT) p = 1;
        unsigned short key = keyW[(size_t)b * PRECT + p];
        float d2 = __uint_as_float(((unsigned)key) << 16);
        float dist = sqrtf(fmaxf(d2, 1e-12f));
        outF[idx] = 1.0f / (1.0f + expf(dist - thrp[0]));
    }
}

// ---------------------------------------------------------------------------
extern "C" void kernel_launch(void* const* d_in, const int* in_sizes, int n_in,
                              void* d_out, int out_size, void* d_ws, size_t ws_size,
                              hipStream_t stream) {
    (void)in_sizes; (void)n_in; (void)out_size; (void)ws_size;
    const float* z   = (const float*)d_in[0];
    const int*   cls = (const int*)d_in[1];
    const float* et  = (const float*)d_in[2];
    const float* W1  = (const float*)d_in[3];
    const float* b1  = (const float*)d_in[4];
    const float* W2  = (const float*)d_in[5];
    const float* b2  = (const float*)d_in[6];
    const float* We  = (const float*)d_in[7];
    const float* be  = (const float*)d_in[8];
    const float* thr = (const float*)d_in[9];
    float* outF = (float*)d_out;

    char* w = (char*)d_ws;
    unsigned char*  hW8   = (unsigned char*)(w + WS_H8);
    float*          sqW   = (float*)(w + WS_SQ);
    short*          W1p   = (short*)(w + WS_W1P);
    short*          W2p   = (short*)(w + WS_W2P);
    short*          Wep   = (short*)(w + WS_WEP);
    short*          t1    = (short*)(w + WS_T1);
    unsigned short* keyW  = (unsigned short*)(w + WS_KEY);
    unsigned*       selP  = (unsigned*)(w + WS_SEL);
    unsigned short* ghist = (unsigned short*)(w + WS_GH);   // aliases dead h
    unsigned*       sbase = (unsigned*)(w + WS_SB);         // aliases dead h
    unsigned*       Tbuf  = (unsigned*)(w + WS_TB);

    pack_all_kernel<<<1504, 256, 0, stream>>>(W1, W2, We, W1p, W2p, Wep, sqW);

    // GEMM1: t1 = relu([z|ce] @ W1 + b1), M=24576, N=512, K=192
    gemm_t<1, 0><<<dim3(192, 4), 256, 0, stream>>>(
        nullptr, z, cls, et, W1p, b1, nullptr, t1, nullptr, 192, 512, 1);
    // GEMM2: x = t1 @ W2 + b2 -> d_out f32, M=24576, N=256, K=512
    gemm_t<0, 0><<<dim3(192, 2), 256, 0, stream>>>(
        t1, nullptr, nullptr, nullptr, W2p, b2, outF + OFF_X, nullptr, nullptr,
        512, 256, 0);
    // GEMM3: h = relu(x @ We + be) -> ws fp8 + sq, M=24576, N=512, K=256
    gemm_t<2, 1><<<dim3(192, 4), 256, 0, stream>>>(
        nullptr, outF + OFF_X, nullptr, nullptr, Wep, be, nullptr, hW8, sqW,
        256, 512, 1);

    gram_mfma_kernel<<<dim3(64, 21), 256, 33792, stream>>>(hW8, sqW, keyW);
    selA_kernel<<<dim3(64, NSLICE), 1024, 0, stream>>>(keyW, ghist);
    selB_kernel<<<64, 1024, 0, stream>>>(ghist, sbase, Tbuf);
    selC_kernel<<<dim3(64, NSLICE), 1024, 0, stream>>>(keyW, sbase, Tbuf, selP);
    int emitN = TOT - OFF_E;
    emit_kernel<<<(emitN + 255) / 256, 256, 0, stream>>>(keyW, selP, thr, outF);
}